// Round 1
// baseline (1732.535 us; speedup 1.0000x reference)
//
#include <hip/hip_runtime.h>

// Morphological skeleton, 16 x 1 x 1024 x 1024 f32.
// skel = sum_{k=0..20} ( e_k - dilate3x3(e_{k+1}) ),  e_0 = x, e_{k+1} = erode3x3(e_k).
// erode/dilate windows clamp at image borders (SAME reduce_window with +-inf init).
//
// Baseline structure: 21 launches of one fused "open step" kernel:
//   reads e_k, computes erode (with border clamp), dilate of the erode result
//   (out-of-image erode values masked to -BIG so they can't win the max),
//   accumulates skel term into d_out (k==0 overwrites -> handles 0xAA poison),
//   writes e_{k+1} to the ping-pong workspace buffer.

static constexpr int Himg = 1024, Wimg = 1024, NIMG = 16;
static constexpr int TILE = 64;
static constexpr int S    = TILE + 4;   // 68: tile + halo 2 (erode 1 + dilate 1)
static constexpr int SP   = S + 1;      // padded LDS stride (69, odd -> no 2^k bank stride)
static constexpr float BIG = 3.0e38f;

__global__ __launch_bounds__(256)
void open_step(const float* __restrict__ ein, float* __restrict__ eout,
               float* __restrict__ skel, int first)
{
    __shared__ float A[S * SP];   // e_k tile with halo 2; out-of-image = +BIG
    __shared__ float B[S * SP];   // erode result on [1,S-1)^2; out-of-image = -BIG

    const int img = blockIdx.z;
    const int y0 = blockIdx.y * TILE - 2;
    const int x0 = blockIdx.x * TILE - 2;
    const float* __restrict__ src = ein + (size_t)img * Himg * Wimg;

    // ---- load e_k tile (+BIG outside the image: min-identity) ----
    for (int idx = threadIdx.x; idx < S * S; idx += 256) {
        int i = idx / S, j = idx - i * S;
        int gi = y0 + i, gj = x0 + j;
        float v = BIG;
        if ((unsigned)gi < (unsigned)Himg && (unsigned)gj < (unsigned)Wimg)
            v = src[(size_t)gi * Wimg + gj];
        A[i * SP + j] = v;
    }
    __syncthreads();

    // ---- erode: 3x3 min of A -> B over [1, S-1)^2 ----
    // Out-of-image positions get -BIG: they must never win the subsequent max.
    // (Treating them as the min over their in-image neighbors is WRONG for
    //  dilation: that min can exceed every legitimate dilation candidate.)
    for (int idx = threadIdx.x; idx < (S - 2) * (S - 2); idx += 256) {
        int i = idx / (S - 2) + 1;
        int j = idx - (i - 1) * (S - 2) + 1;
        int gi = y0 + i, gj = x0 + j;
        float m;
        if ((unsigned)gi < (unsigned)Himg && (unsigned)gj < (unsigned)Wimg) {
            const float* a = &A[(i - 1) * SP + (j - 1)];
            float r0 = fminf(fminf(a[0],      a[1]),      a[2]);
            float r1 = fminf(fminf(a[SP],     a[SP + 1]), a[SP + 2]);
            float r2 = fminf(fminf(a[2 * SP], a[2*SP+1]), a[2*SP+2]);
            m = fminf(fminf(r0, r1), r2);
        } else {
            m = -BIG;
        }
        B[i * SP + j] = m;
    }
    __syncthreads();

    // ---- dilate B, accumulate skel term, store e_{k+1} ----
    float* __restrict__ sk = skel + (size_t)img * Himg * Wimg;
    float* __restrict__ eo = eout + (size_t)img * Himg * Wimg;
    for (int idx = threadIdx.x; idx < TILE * TILE; idx += 256) {
        int i = (idx >> 6) + 2, j = (idx & 63) + 2;
        const float* b = &B[(i - 1) * SP + (j - 1)];
        float r0 = fmaxf(fmaxf(b[0],      b[1]),      b[2]);
        float r1 = fmaxf(fmaxf(b[SP],     b[SP + 1]), b[SP + 2]);
        float r2 = fmaxf(fmaxf(b[2 * SP], b[2*SP+1]), b[2*SP+2]);
        float d  = fmaxf(fmaxf(r0, r1), r2);

        int gi = y0 + i, gj = x0 + j;           // tile interior: always in-image
        size_t off = (size_t)gi * Wimg + gj;
        float term = A[i * SP + j] - d;         // e_k - dilate(e_{k+1})
        sk[off] = first ? term : (sk[off] + term);
        eo[off] = B[i * SP + j];                // e_{k+1}
    }
}

extern "C" void kernel_launch(void* const* d_in, const int* in_sizes, int n_in,
                              void* d_out, int out_size, void* d_ws, size_t ws_size,
                              hipStream_t stream)
{
    const float* x  = (const float*)d_in[0];
    float* skel     = (float*)d_out;
    const size_t n  = (size_t)NIMG * Himg * Wimg;

    // ping-pong erosion buffers in workspace (needs 2*n*4 = 128 MiB)
    float* e0 = (float*)d_ws;
    float* e1 = e0 + n;

    dim3 grid(Wimg / TILE, Himg / TILE, NIMG);
    dim3 block(256);

    const float* cur = x;
    float* nxt = e0;
    for (int k = 0; k <= 20; ++k) {
        open_step<<<grid, block, 0, stream>>>(cur, nxt, skel, k == 0 ? 1 : 0);
        cur = nxt;
        nxt = (nxt == e0) ? e1 : e0;
    }
}

// Round 2
// 393.466 us; speedup vs baseline: 4.4033x; 4.4033x over previous
//
#include <hip/hip_runtime.h>

// Morphological skeleton, 16 x 1024 x 1024 f32.
// skel = sum_{k=0..20} ( e_k - dilate3x3(e_{k+1}) ),  e_0 = x, e_{k+1} = erode3x3(e_k)
// (windows clamp at image borders).
//
// Round-2 structure: 3 dispatches x G=7 fused steps. Per block: 80x80 LDS tile
// (tile 64 + halo 8), ping-pong A/B. Per step: separable erode (vertical min in
// regs from 3 aligned b128 reads, horizontal min via __shfl lane+-1), OOB->+BIG
// mask; then separable dilate of e_{m+1} (OOB->-BIG) + skel-term accumulation
// in registers. Valid region shrinks 1 px/step == needed region (garbage creep
// at tile edges is provably never read by valid outputs).
// SP=80 (no pad): every row*80+4*jc offset is 16B-aligned -> true ds_*_b128.
// LDS 2*25.6KB -> 3 blocks/CU.

static constexpr int Himg = 1024, Wimg = 1024;
static constexpr int TILE = 64, HALO = 8;      // HALO = G+1
static constexpr int S = TILE + 2 * HALO;      // 80
static constexpr int SP = S;                   // 80: keeps b128 alignment
static constexpr int G = 7;
static constexpr float BIG = 3.0e38f;

__device__ __forceinline__ float min3(float a, float b, float c) {
    return fminf(fminf(a, b), c);
}
__device__ __forceinline__ float max3(float a, float b, float c) {
    return fmaxf(fmaxf(a, b), c);
}

__global__ __launch_bounds__(512, 4)
void skel_group(const float* __restrict__ ein, float* __restrict__ eout,
                float* __restrict__ skel, int first, int write_e)
{
    __shared__ __align__(16) float buf0[S * SP];
    __shared__ __align__(16) float buf1[S * SP];
    float* A = buf0;
    float* B = buf1;

    const int img = blockIdx.z;
    const int gy0 = blockIdx.y * TILE;
    const int gx0 = blockIdx.x * TILE;
    const size_t base = (size_t)img * Himg * Wimg;
    const float* __restrict__ src = ein + base;

    const int tid = threadIdx.x;
    const int wv = tid >> 6, ln = tid & 63;

    // ---- load e tile: LDS (i,j) <-> global (gy0+i-8, gx0+j-8); OOB = +BIG ----
    for (int c = tid; c < (S / 4) * S; c += 512) {     // 20 chunks x 80 rows
        int i = c / 20, jc = c - i * 20;
        int gi = gy0 + i - HALO;
        int gj = gx0 + 4 * jc - HALO;
        float4 v;
        if ((unsigned)gi < (unsigned)Himg && gj >= 0 && gj + 3 < Wimg) {
            v = *(const float4*)&src[(size_t)gi * Wimg + gj];
        } else if ((unsigned)gi < (unsigned)Himg) {
            v.x = ((unsigned)(gj + 0) < (unsigned)Wimg) ? src[(size_t)gi * Wimg + gj + 0] : BIG;
            v.y = ((unsigned)(gj + 1) < (unsigned)Wimg) ? src[(size_t)gi * Wimg + gj + 1] : BIG;
            v.z = ((unsigned)(gj + 2) < (unsigned)Wimg) ? src[(size_t)gi * Wimg + gj + 2] : BIG;
            v.w = ((unsigned)(gj + 3) < (unsigned)Wimg) ? src[(size_t)gi * Wimg + gj + 3] : BIG;
        } else {
            v = make_float4(BIG, BIG, BIG, BIG);
        }
        *(float4*)&A[i * SP + 4 * jc] = v;
    }
    __syncthreads();

    float4 acc[2];
    acc[0] = make_float4(0.f, 0.f, 0.f, 0.f);
    acc[1] = make_float4(0.f, 0.f, 0.f, 0.f);

    for (int m = 0; m < G; ++m) {
        // ---- erode A -> B over rows [1,79), 20 chunks; 60 active lanes/wave ----
        if (ln < 60) {
            int rr = ln / 20, jc = ln - 20 * rr;
            for (int T = wv; T < 26; T += 8) {
                int row = 1 + 3 * T + rr;            // 1..78
                int o = row * SP + 4 * jc;
                float4 am = *(float4*)&A[o - SP];
                float4 a0 = *(float4*)&A[o];
                float4 ap = *(float4*)&A[o + SP];
                float4 vm;
                vm.x = min3(am.x, a0.x, ap.x);
                vm.y = min3(am.y, a0.y, ap.y);
                vm.z = min3(am.z, a0.z, ap.z);
                vm.w = min3(am.w, a0.w, ap.w);
                float lft = __shfl(vm.w, ln - 1);    // jc==0: garbage, tolerated
                float rgt = __shfl(vm.x, ln + 1);    // jc==19: garbage, tolerated
                float4 e;
                e.x = min3(lft,  vm.x, vm.y);
                e.y = min3(vm.x, vm.y, vm.z);
                e.z = min3(vm.y, vm.z, vm.w);
                e.w = min3(vm.z, vm.w, rgt);
                // out-of-image positions must stay +BIG
                int gi = gy0 + row - HALO;
                int gj = gx0 + 4 * jc - HALO;
                bool rok = (unsigned)gi < (unsigned)Himg;
                e.x = (rok && (unsigned)(gj + 0) < (unsigned)Wimg) ? e.x : BIG;
                e.y = (rok && (unsigned)(gj + 1) < (unsigned)Wimg) ? e.y : BIG;
                e.z = (rok && (unsigned)(gj + 2) < (unsigned)Wimg) ? e.z : BIG;
                e.w = (rok && (unsigned)(gj + 3) < (unsigned)Wimg) ? e.w : BIG;
                *(float4*)&B[o] = e;
            }
        }
        __syncthreads();

        // ---- dilate B (OOB = -BIG) + accumulate skel term; 4 rows x 16 chunks ----
        {
            int rr = ln >> 4, jc = ln & 15;
#pragma unroll
            for (int s = 0; s < 2; ++s) {
                int T = wv + 8 * s;
                int row = HALO + 4 * T + rr;         // 8..71  (always in-image)
                int j0 = HALO + 4 * jc;              // 8..68
                int o = row * SP + j0;
                int grow = gy0 + row - HALO;
                bool rm_ok = (grow - 1) >= 0;
                bool rp_ok = (grow + 1) < Himg;
                float4 bm = *(float4*)&B[o - SP];
                float4 b0 = *(float4*)&B[o];
                float4 bp = *(float4*)&B[o + SP];
                if (!rm_ok) bm = make_float4(-BIG, -BIG, -BIG, -BIG);
                if (!rp_ok) bp = make_float4(-BIG, -BIG, -BIG, -BIG);
                float4 vx;
                vx.x = max3(bm.x, b0.x, bp.x);
                vx.y = max3(bm.y, b0.y, bp.y);
                vx.z = max3(bm.z, b0.z, bp.z);
                vx.w = max3(bm.w, b0.w, bp.w);
                float lft = __shfl(vx.w, ln - 1);
                float rgt = __shfl(vx.x, ln + 1);
                if (jc == 0) {                        // col j0-1 == 7 (real halo)
                    if (gx0 == 0) lft = -BIG;         // global col -1
                    else {
                        float t0 = rm_ok ? B[o - SP - 1] : -BIG;
                        float t1 = B[o - 1];
                        float t2 = rp_ok ? B[o + SP - 1] : -BIG;
                        lft = max3(t0, t1, t2);
                    }
                }
                if (jc == 15) {                       // col j0+4 == 72
                    if (gx0 + TILE >= Wimg) rgt = -BIG;  // global col 1024
                    else {
                        float t0 = rm_ok ? B[o - SP + 4] : -BIG;
                        float t1 = B[o + 4];
                        float t2 = rp_ok ? B[o + SP + 4] : -BIG;
                        rgt = max3(t0, t1, t2);
                    }
                }
                float4 d;
                d.x = max3(lft,  vx.x, vx.y);
                d.y = max3(vx.x, vx.y, vx.z);
                d.z = max3(vx.y, vx.z, vx.w);
                d.w = max3(vx.z, vx.w, rgt);
                float4 a0r = *(float4*)&A[o];        // e_m at this px
                acc[s].x += a0r.x - d.x;
                acc[s].y += a0r.y - d.y;
                acc[s].z += a0r.z - d.z;
                acc[s].w += a0r.w - d.w;
            }
        }
        __syncthreads();
        float* t = A; A = B; B = t;                  // A := e_{m+1}
    }

    // ---- write skel (same mapping as dilate loop) ----
    float* __restrict__ sk = skel + base;
    {
        int rr = ln >> 4, jc = ln & 15;
#pragma unroll
        for (int s = 0; s < 2; ++s) {
            int T = wv + 8 * s;
            int grow = gy0 + 4 * T + rr;
            int gcol = gx0 + 4 * jc;
            size_t off = (size_t)grow * Wimg + gcol;
            float4 v = acc[s];
            if (!first) {
                float4 old = *(const float4*)&sk[off];
                v.x += old.x; v.y += old.y; v.z += old.z; v.w += old.w;
            }
            *(float4*)&sk[off] = v;
        }
    }

    // ---- write e_{k+7} tile (skipped in last group) ----
    if (write_e) {
        float* __restrict__ eo = eout + base;
        for (int c = tid; c < (TILE / 4) * TILE; c += 512) {  // 16 chunks x 64 rows
            int row = c >> 4, jc = c & 15;
            int o = (HALO + row) * SP + HALO + 4 * jc;
            *(float4*)&eo[(size_t)(gy0 + row) * Wimg + gx0 + 4 * jc] = *(float4*)&A[o];
        }
    }
}

extern "C" void kernel_launch(void* const* d_in, const int* in_sizes, int n_in,
                              void* d_out, int out_size, void* d_ws, size_t ws_size,
                              hipStream_t stream)
{
    const float* x = (const float*)d_in[0];
    float* skel = (float*)d_out;
    const size_t n = (size_t)16 * Himg * Wimg;

    float* e0 = (float*)d_ws;
    float* e1 = e0 + n;

    dim3 grid(Wimg / TILE, Himg / TILE, 16);
    dim3 block(512);

    // steps 0-6: x -> e0 ; steps 7-13: e0 -> e1 ; steps 14-20: e1 -> (none)
    skel_group<<<grid, block, 0, stream>>>(x,  e0, skel, 1, 1);
    skel_group<<<grid, block, 0, stream>>>(e0, e1, skel, 0, 1);
    skel_group<<<grid, block, 0, stream>>>(e1, e0, skel, 0, 0);
}

// Round 4
// 376.860 us; speedup vs baseline: 4.5973x; 1.0441x over previous
//
#include <hip/hip_runtime.h>

// Morphological skeleton, 16 x 1024 x 1024 f32.
// skel = sum_{k=0..20} ( e_k - dilate3x3(e_{k+1}) ),  e_0 = x, e_{k+1} = erode3x3(e_k)
// (reduce_window SAME semantics: windows clamp at image borders).
//
// Register-resident vertical pipeline, zero LDS tile. 3 dispatches x G=7 fused
// erosion stages. One wave (64 lanes x float4) owns a 256-col band and sweeps
// 80 rows (64 output + warm-up/drain). Per stage: 2-row register buffer
// (parity-swapped); erode = v_min3 vertical + shfl lane+-1 horizontal; dilate
// of f_{s+1} reuses stage s+1's buffers (read before their update); terms go
// into an 8-deep register FIFO, emitted as rows complete.
//
// Round-4 fixes vs round 3:
//  - band 4 starts at 768 (was 784): gx max = 1020, no out-of-bounds lane 63
//    accesses (root cause of the round-3 memory-fault abort).
//  - skel-old prefetch moved AFTER emission: slot skpf[PFI] written at step t
//    (row t-6) is consumed at step t+2 (emitting row t-6); the old top-of-step
//    placement clobbered the value one step before its use.
//
// Correctness invariants (desk-verified):
//  - synthetic erode values at OOB/warm-up rows are >= the true clamped
//    erosion (dependency-cone subset) => harmless in the min chain; masked to
//    -BIG in the dilate max via wave-uniform row conditionals (topOK/botOK).
//  - halos exactly tight: 8 rows warm-up (t0 = y0-8), 8 cols/side shrink;
//    bands own disjoint column ranges {[0,248),[248,488),[488,728),[728,968),
//    [968,1024)} so the skel read-modify-write never races.

static constexpr int W = 1024, H = 1024, NIMG = 16;
static constexpr int RCH = 64;           // output rows per wave
static constexpr int NSTEP = RCH + 16;   // 80 sweep steps
static constexpr float BIG = 3.0e38f;

__device__ __forceinline__ float min3f(float a, float b, float c) { return fminf(fminf(a, b), c); }
__device__ __forceinline__ float max3f(float a, float b, float c) { return fmaxf(fmaxf(a, b), c); }

template<bool FIRST, bool WRITE_E, int PFI>
__device__ __forceinline__
void pipe_step(int t, int y0, int lane, int gx,
               bool leftEdge, bool rightEdge, bool lane_ok,
               const float* __restrict__ in, float* __restrict__ eo,
               float* __restrict__ sk,
               float4 (&OB)[7], float4 (&MB)[7], float4& OD, float4& MD,
               float4 (&acc)[8], float4 (&pf)[2], float4 (&skpf)[2])
{
    // consume input row t (OOB rows are +BIG: erode identity)
    float4 cur;
    if ((unsigned)t < (unsigned)H) cur = pf[PFI];
    else                           cur = make_float4(BIG, BIG, BIG, BIG);
    // prefetch input row t+2 into the slot just consumed
    {
        const int nr = t + 2;
        if ((unsigned)nr < (unsigned)H && nr <= y0 + RCH + 7)
            pf[PFI] = *(const float4*)&in[(size_t)nr * W + gx];
    }

#pragma unroll
    for (int s = 0; s < 7; ++s) {
        // invariant at entry: OB[s] = f_s(t-s-2), MB[s] = f_s(t-s-1),
        // cur = f_s(t-s) (produced this step by the previous stage / load).
        const float4 fOld = OB[s];
        const float4 fMid = MB[s];

        // ---- erode: en = f_{s+1}(t-s-1) ----
        float4 vm;
        vm.x = min3f(fOld.x, fMid.x, cur.x);
        vm.y = min3f(fOld.y, fMid.y, cur.y);
        vm.z = min3f(fOld.z, fMid.z, cur.z);
        vm.w = min3f(fOld.w, fMid.w, cur.w);
        float lft = __shfl(vm.w, lane - 1);   // lane 0: garbage -> invalid cols
        float rgt = __shfl(vm.x, lane + 1);   // lane 63: garbage -> invalid cols
        if (leftEdge)  lft = BIG;             // true image border clamp
        if (rightEdge) rgt = BIG;
        float4 en;
        en.x = min3f(lft,  vm.x, vm.y);
        en.y = min3f(vm.x, vm.y, vm.z);
        en.z = min3f(vm.y, vm.z, vm.w);
        en.w = min3f(vm.z, vm.w, rgt);

        OB[s] = cur;   // old-role slot receives newest f_s row (parity swap)

        // ---- dilate of f_{s+1} centered at row t-s-2 ----
        // gOld/gMid from stage s+1's buffers, read BEFORE their update in
        // iteration s+1 of this same step.
        float4 gOld, gMid;
        if (s < 6) { gOld = OB[s + 1]; gMid = MB[s + 1]; }  // f_{s+1}(t-s-3), (t-s-2)
        else       { gOld = OD;        gMid = MD;        }
        const bool topOK = (t - s - 3) >= 0;   // row t-s-3 in-image?
        const bool botOK = (t - s - 1) < H;    // row t-s-1 in-image?
        float4 vx;
        {
            float txx = topOK ? gOld.x : -BIG, bxx = botOK ? en.x : -BIG;
            float txy = topOK ? gOld.y : -BIG, bxy = botOK ? en.y : -BIG;
            float txz = topOK ? gOld.z : -BIG, bxz = botOK ? en.z : -BIG;
            float txw = topOK ? gOld.w : -BIG, bxw = botOK ? en.w : -BIG;
            vx.x = max3f(txx, gMid.x, bxx);
            vx.y = max3f(txy, gMid.y, bxy);
            vx.z = max3f(txz, gMid.z, bxz);
            vx.w = max3f(txw, gMid.w, bxw);
        }
        float dl = __shfl(vx.w, lane - 1);
        float dr = __shfl(vx.x, lane + 1);
        if (leftEdge)  dl = -BIG;
        if (rightEdge) dr = -BIG;
        float4 dn;
        dn.x = max3f(dl,   vx.x, vx.y);
        dn.y = max3f(vx.x, vx.y, vx.z);
        dn.z = max3f(vx.y, vx.z, vx.w);
        dn.w = max3f(vx.z, vx.w, dr);

        // term_s(t-s-2) = f_s(t-s-2) - dilate(f_{s+1})(t-s-2); FIFO slot 6-s
        acc[6 - s].x += fOld.x - dn.x;
        acc[6 - s].y += fOld.y - dn.y;
        acc[6 - s].z += fOld.z - dn.z;
        acc[6 - s].w += fOld.w - dn.w;

        if (s == 6) {
            if (WRITE_E) {
                const int er = t - 7;          // en = f_7(t-7)
                if (er >= y0 && er < y0 + RCH && lane_ok)
                    *(float4*)&eo[(size_t)er * W + gx] = en;
            }
            OD = en;
        }
        cur = en;   // becomes f_{s+1}(t-(s+1)) for the next stage
    }

    // ---- emit completed row t-8 ----
    if (t >= y0 + 8) {
        const int r = t - 8;
        float4 v = acc[0];
        if (!FIRST) {
            const float4 o = skpf[PFI];        // skel row t-8, prefetched at step t-2
            v.x += o.x; v.y += o.y; v.z += o.z; v.w += o.w;
        }
        if (lane_ok)
            *(float4*)&sk[(size_t)r * W + gx] = v;
    }
#pragma unroll
    for (int j = 0; j < 7; ++j) acc[j] = acc[j + 1];
    acc[7] = make_float4(0.f, 0.f, 0.f, 0.f);

    // ---- prefetch old skel row t-6 AFTER emission (consumed at step t+2,
    //      which shares this step's parity and thus this PFI slot) ----
    if (!FIRST) {
        const int pr = t - 6;
        if (pr >= y0 && pr < y0 + RCH)
            skpf[PFI] = *(const float4*)&sk[(size_t)pr * W + gx];
    }
}

template<bool FIRST, bool WRITE_E>
__global__ __launch_bounds__(64)
void skel_pipe(const float* __restrict__ ein, float* __restrict__ eout,
               float* __restrict__ skel)
{
    const int lane = threadIdx.x;          // one wave per block
    const int bx = blockIdx.x;             // band 0..4
    const int y0 = blockIdx.y * RCH;       // row chunk
    const int img = blockIdx.z;
    const int x0 = (bx == 4) ? 768 : bx * 240;   // last band starts at 1024-256
    const int gx = x0 + 4 * lane;                // gx max = 768 + 252 = 1020

    const size_t base = (size_t)img * (size_t)(W * H);
    const float* __restrict__ in = ein + base;
    float* __restrict__ eo = eout + base;
    float* __restrict__ sk = skel + base;

    const bool leftEdge  = (gx == 0);
    const bool rightEdge = (gx + 4 == W);
    // disjoint write ownership (bands overlap in compute, never in writes)
    const int own_lo = (bx == 0) ? 0 : ((bx == 4) ? 968 : x0 + 8);
    const int own_hi = (bx == 4) ? W : x0 + 248;
    const bool lane_ok = (gx >= own_lo) && (gx < own_hi);

    float4 B0[7], B1[7], D0, D1, acc[8], pf[2], skpf[2];
    const float4 big4 = make_float4(BIG, BIG, BIG, BIG);
    const float4 z4   = make_float4(0.f, 0.f, 0.f, 0.f);
#pragma unroll
    for (int s = 0; s < 7; ++s) { B0[s] = big4; B1[s] = big4; }
    D0 = big4; D1 = big4;
#pragma unroll
    for (int j = 0; j < 8; ++j) acc[j] = z4;
    pf[0] = big4; pf[1] = big4; skpf[0] = z4; skpf[1] = z4;

    // prefetch input rows t0, t0+1
    {
        const int r0 = y0 - 8, r1 = y0 - 7;
        if (r0 >= 0) pf[0] = *(const float4*)&in[(size_t)r0 * W + gx];
        if (r1 >= 0) pf[1] = *(const float4*)&in[(size_t)r1 * W + gx];
    }

    const int t0 = y0 - 8;   // even (y0 multiple of 64) -> parity mapping holds
#pragma unroll 1
    for (int t = t0; t < t0 + NSTEP; t += 2) {
        pipe_step<FIRST, WRITE_E, 0>(t,     y0, lane, gx, leftEdge, rightEdge, lane_ok,
                                     in, eo, sk, B0, B1, D0, D1, acc, pf, skpf);
        pipe_step<FIRST, WRITE_E, 1>(t + 1, y0, lane, gx, leftEdge, rightEdge, lane_ok,
                                     in, eo, sk, B1, B0, D1, D0, acc, pf, skpf);
    }
}

extern "C" void kernel_launch(void* const* d_in, const int* in_sizes, int n_in,
                              void* d_out, int out_size, void* d_ws, size_t ws_size,
                              hipStream_t stream)
{
    const float* x = (const float*)d_in[0];
    float* skel = (float*)d_out;
    const size_t n = (size_t)NIMG * W * H;

    float* e0 = (float*)d_ws;
    float* e1 = e0 + n;

    dim3 grid(5, H / RCH, NIMG);
    dim3 block(64);

    // steps 0-6: x -> e0 ; 7-13: e0 -> e1 ; 14-20: e1 -> (none)
    skel_pipe<true,  true ><<<grid, block, 0, stream>>>(x,  e0, skel);
    skel_pipe<false, true ><<<grid, block, 0, stream>>>(e0, e1, skel);
    skel_pipe<false, false><<<grid, block, 0, stream>>>(e1, e0, skel);
}